// Round 2
// baseline (149.320 us; speedup 1.0000x reference)
//
#include <hip/hip_runtime.h>

#define Bn 32
#define Cn 64
#define Hn 56
#define Wn 56
#define REPN 50
#define NKn 17
#define HWn (Hn*Wn)           // 3136
#define NSTATf 100352.0f      // B*H*W
#define EPSf 1e-5f

// LDS tile: rows = padded-input rows -2..57 (60 rows), data cols at 4+icol.
// Row stride 68 (not 64) so row-stride mod 32 banks != 0 -> b128 pattern
// spreads over bank groups. 68%4==0 keeps float4 stores 16B-aligned.
#define TSTR 68
#define TROWS 60
#define TSZ (TROWS*TSTR)      // 4080 floats = 16320 B

#define WEFF_OFF 0            // REPN*63 floats: [r][t(7)][9]
#define STATS_OFF 3200        // 6*REPN floats: [q(6)][r]

#define NQ 784                // 56 rows * 14 quads

// ---------------------------------------------------------------- K0: weights
__global__ void k_weff(const float* __restrict__ w0, const float* __restrict__ w1,
                       const int* __restrict__ Mh, const int* __restrict__ Mv,
                       const int* __restrict__ Mid, float* __restrict__ ws)
{
    int idx = blockIdx.x * blockDim.x + threadIdx.x;
    if (idx < 6*REPN) ws[STATS_OFF + idx] = 0.f;
    if (idx >= REPN*63) return;
    int r   = idx / 63;
    int rem = idx % 63;
    int t   = rem / 9;
    int ij  = rem % 9;
    const int* M = (t < 3) ? (Mh + (t*REPN + r)*NKn)
                 : (t < 6) ? (Mv + ((t-3)*REPN + r)*NKn)
                           : (Mid + r*NKn);
    float acc = 0.f;
    for (int k = 0; k < NKn; ++k) {
        int m = M[k];
        if (m) acc += (float)m * (w0[(r*NKn + k)*9 + ij] + w1[(r*NKn + k)*9 + ij]);
    }
    ws[WEFF_OFF + idx] = acc;
}

// ------------------------------------------------------------- tile staging
__device__ __forceinline__ void load_tile(const float* __restrict__ src,
                                          float* __restrict__ tile, int tid)
{
    for (int i = tid; i < TSZ/4; i += 256) *(float4*)(tile + 4*i) = make_float4(0,0,0,0);
    __syncthreads();
    const float4* s4 = (const float4*)src;
    for (int i = tid; i < HWn/4; i += 256) {
        float4 v = s4[i];
        int e = i * 4;
        int row = e / Wn;
        int col = e % Wn;                       // multiple of 4 (56%4==0)
        *(float4*)(tile + (2 + row)*TSTR + 4 + col) = v;
    }
    __syncthreads();
}

// ------------------------------------------------------- core: 4 px per call
// Quad-task g: h = g/14, w0 = 4*(g%14); pixels (h, w0..w0+3).
// lora1 = Wh0@(h+1,w+1) + Wh1@(h, w-1|57) + Wh2@(h-1|57, w)
// lora2 = Wv0@(h+1,w+1) + Wv1@(h-1|57, w) + Wv2@(h, w-1|57)
// small = Wid@(h+1,w+1)
// Padded pos y,x -> tile rows y..y+2, tile cols x+2..x+4.
// Logical rows R[d] = tile row h+d (d=0..3); R[-1] = (h==0 ? 57 : h-1).
//  d=-1: posB wrow0
//  d=0 : posA wrow0;  posB wrow1 (zeroed if h==0)
//  d=1 : pos0 wrow0;  posA wrow1; posB wrow2 (zeroed if h==0)
//  d=2 : pos0 wrow1;  posA wrow2;  (also residual rep_in = cols 4..7)
//  d=3 : pos0 wrow2
// w==0 (wq==0, pixel 0): regular posA path reads zero-pad cols 1..3; the
// wrap contribution is col 59 (input col 55) at rows h..h+2, col-index j=0.
__device__ __forceinline__ void conv_quad(const float* __restrict__ tile,
        const float* __restrict__ wk, int g,
        float* __restrict__ l1, float* __restrict__ l2,
        float* __restrict__ sm, float* __restrict__ res)
{
    int h  = g / 14;
    int wq = g - h*14;
    int w0 = wq * 4;
    bool topwrap = (h == 0);
    #pragma unroll
    for (int p = 0; p < 4; ++p) { l1[p]=0.f; l2[p]=0.f; sm[p]=0.f; }

    {   // d = -1 row
        int row = topwrap ? 57 : (h-1);
        const float* rp = tile + row*TSTR + w0;
        float4 qa = *(const float4*)rp;
        float4 qb = *(const float4*)(rp+4);
        float X[8] = {qa.x,qa.y,qa.z,qa.w,qb.x,qb.y,qb.z,qb.w};
        #pragma unroll
        for (int p = 0; p < 4; ++p)
            #pragma unroll
            for (int j = 0; j < 3; ++j) {
                float v = X[2+p+j];
                l1[p] = fmaf(v, wk[18+j], l1[p]);
                l2[p] = fmaf(v, wk[36+j], l2[p]);
            }
    }
    #pragma unroll
    for (int d = 0; d < 4; ++d) {
        const float* rp = tile + (h+d)*TSTR + w0;
        float4 qa = *(const float4*)rp;
        float4 qb = *(const float4*)(rp+4);
        float X[9] = {qa.x,qa.y,qa.z,qa.w,qb.x,qb.y,qb.z,qb.w,0.f};
        if (d >= 1) X[8] = rp[8];
        if (d == 2) { res[0]=X[4]; res[1]=X[5]; res[2]=X[6]; res[3]=X[7]; }
        if (d <= 1) {   // posB wrow d+1 (masked when h==0)
            #pragma unroll
            for (int p = 0; p < 4; ++p)
                #pragma unroll
                for (int j = 0; j < 3; ++j) {
                    float v = topwrap ? 0.f : X[2+p+j];
                    l1[p] = fmaf(v, wk[21+3*d+j], l1[p]);
                    l2[p] = fmaf(v, wk[39+3*d+j], l2[p]);
                }
        }
        if (d <= 2) {   // posA wrow d
            #pragma unroll
            for (int p = 0; p < 4; ++p)
                #pragma unroll
                for (int j = 0; j < 3; ++j) {
                    float v = X[1+p+j];
                    l1[p] = fmaf(v, wk[9+3*d+j],  l1[p]);
                    l2[p] = fmaf(v, wk[45+3*d+j], l2[p]);
                }
        }
        if (d >= 1) {   // pos0 wrow d-1
            #pragma unroll
            for (int p = 0; p < 4; ++p)
                #pragma unroll
                for (int j = 0; j < 3; ++j) {
                    float v = X[3+p+j];
                    l1[p] = fmaf(v, wk[3*(d-1)+j],    l1[p]);
                    l2[p] = fmaf(v, wk[27+3*(d-1)+j], l2[p]);
                    sm[p] = fmaf(v, wk[54+3*(d-1)+j], sm[p]);
                }
        }
    }
    if (wq == 0) {  // w==0 wrap correction, pixel 0 only
        #pragma unroll
        for (int d = 0; d < 3; ++d) {
            float v = tile[(h+d)*TSTR + 59];
            l1[0] = fmaf(v, wk[9+3*d],  l1[0]);
            l2[0] = fmaf(v, wk[45+3*d], l2[0]);
        }
    }
}

// ---------------------------------------------------------------- K1: stats
__global__ void __launch_bounds__(256) k_stats(const float* __restrict__ in,
        const int* __restrict__ rep_idx, const float* __restrict__ weff,
        float* __restrict__ stats)
{
    __shared__ __align__(16) float tile[TSZ];
    __shared__ float red[4][6];
    int bid = blockIdx.x;
    int r = bid % REPN;
    int b = bid / REPN;
    int tid = threadIdx.x;
    int cin = rep_idx[r];
    load_tile(in + ((size_t)(b*Cn + cin))*HWn, tile, tid);

    float wk[63];
    const float* wr = weff + r*63;
    #pragma unroll
    for (int i = 0; i < 63; ++i) wk[i] = wr[i];

    float s1=0.f,q1=0.f,s2=0.f,q2=0.f,s3=0.f,q3=0.f;
    for (int g = tid; g < NQ; g += 256) {
        float l1[4], l2[4], sm[4], res[4];
        conv_quad(tile, wk, g, l1, l2, sm, res);
        #pragma unroll
        for (int p = 0; p < 4; ++p) {
            s1 += l1[p]; q1 += l1[p]*l1[p];
            s2 += l2[p]; q2 += l2[p]*l2[p];
            s3 += sm[p]; q3 += sm[p]*sm[p];
        }
    }
    float vals[6] = {s1,q1,s2,q2,s3,q3};
    int lane = tid & 63, wave = tid >> 6;
    #pragma unroll
    for (int q = 0; q < 6; ++q) {
        float v = vals[q];
        for (int o = 32; o; o >>= 1) v += __shfl_down(v, o, 64);
        if (lane == 0) red[wave][q] = v;
    }
    __syncthreads();
    if (tid < 6)
        atomicAdd(&stats[tid*REPN + r], red[0][tid] + red[1][tid] + red[2][tid] + red[3][tid]);
}

// ---------------------------------------------------------------- K2: output
__global__ void __launch_bounds__(256) k_out(const float* __restrict__ in,
        const int* __restrict__ rep_idx, const int* __restrict__ ghost_idx,
        const float* __restrict__ weff, const float* __restrict__ stats,
        float* __restrict__ out)
{
    __shared__ __align__(16) float tile[TSZ];
    int bid = blockIdx.x;
    int c = bid % Cn;
    int b = bid / Cn;
    int tid = threadIdx.x;

    if (c >= REPN) {                             // ghost channel copy
        int cin = ghost_idx[c - REPN];
        const float4* s4 = (const float4*)(in + ((size_t)(b*Cn + cin))*HWn);
        float4* d4 = (float4*)(out + ((size_t)(b*Cn + c))*HWn);
        for (int i = tid; i < HWn/4; i += 256) d4[i] = s4[i];
        return;
    }

    int r = c;
    int cin = rep_idx[r];
    load_tile(in + ((size_t)(b*Cn + cin))*HWn, tile, tid);

    float wk[63];
    const float* wr = weff + r*63;
    #pragma unroll
    for (int i = 0; i < 63; ++i) wk[i] = wr[i];

    const float inv = 1.0f / NSTATf;
    float m1 = stats[0*REPN+r]*inv, v1 = stats[1*REPN+r]*inv - m1*m1;
    float m2 = stats[2*REPN+r]*inv, v2 = stats[3*REPN+r]*inv - m2*m2;
    float m3 = stats[4*REPN+r]*inv, v3 = stats[5*REPN+r]*inv - m3*m3;
    float r1 = rsqrtf(v1 + EPSf), r2 = rsqrtf(v2 + EPSf), r3 = rsqrtf(v3 + EPSf);

    float* dst = out + ((size_t)(b*Cn + c))*HWn;
    for (int g = tid; g < NQ; g += 256) {
        float l1[4], l2[4], sm[4], res[4];
        conv_quad(tile, wk, g, l1, l2, sm, res);
        int h  = g / 14;
        int w0 = (g - h*14) * 4;
        float4 o;
        o.x = (l1[0]-m1)*r1 + (l2[0]-m2)*r2 + (sm[0]-m3)*r3 + res[0];
        o.y = (l1[1]-m1)*r1 + (l2[1]-m2)*r2 + (sm[1]-m3)*r3 + res[1];
        o.z = (l1[2]-m1)*r1 + (l2[2]-m2)*r2 + (sm[2]-m3)*r3 + res[2];
        o.w = (l1[3]-m1)*r1 + (l2[3]-m2)*r2 + (sm[3]-m3)*r3 + res[3];
        *(float4*)(dst + h*Wn + w0) = o;
    }
}

extern "C" void kernel_launch(void* const* d_in, const int* in_sizes, int n_in,
                              void* d_out, int out_size, void* d_ws, size_t ws_size,
                              hipStream_t stream) {
    const float* in   = (const float*)d_in[0];
    const float* w0   = (const float*)d_in[1];
    const float* w1   = (const float*)d_in[2];
    const int*   Mh   = (const int*)d_in[3];
    const int*   Mv   = (const int*)d_in[4];
    const int*   Mid  = (const int*)d_in[5];
    const int*   ghost= (const int*)d_in[6];
    const int*   rep  = (const int*)d_in[7];
    float* out  = (float*)d_out;
    float* ws   = (float*)d_ws;
    float* weff  = ws + WEFF_OFF;
    float* stats = ws + STATS_OFF;

    k_weff<<<(REPN*63 + 255)/256, 256, 0, stream>>>(w0, w1, Mh, Mv, Mid, ws);
    k_stats<<<Bn*REPN, 256, 0, stream>>>(in, rep, weff, stats);
    k_out<<<Bn*Cn, 256, 0, stream>>>(in, rep, ghost, weff, stats, out);
}

// Round 3
// 136.039 us; speedup vs baseline: 1.0976x; 1.0976x over previous
//
#include <hip/hip_runtime.h>

#define Bn 32
#define Cn 64
#define Hn 56
#define Wn 56
#define REPN 50
#define NKn 17
#define HWn (Hn*Wn)           // 3136
#define NSTATf 100352.0f      // B*H*W
#define EPSf 1e-5f

// LDS tile: rows = padded-input rows -2..57 (60 rows), data cols at 4+icol.
#define TSTR 68
#define TROWS 60
#define TSZ (TROWS*TSTR)      // 4080 floats

#define NQ 784                // 56 rows * 14 quads (4 px per quad-task)

// ws layout (floats). Planes hold conv results, computed ONCE.
#define PLANE (Bn*REPN*HWn)   // 5,017,600 floats = 20.07 MB
#define L1_OFF 0
#define L2_OFF PLANE
#define SM_OFF (2*PLANE)
#define PART_OFF (3*PLANE)    // partial stats: [q(6)][r(50)][b(32)] = 9600 floats
// total ws use: ~60.3 MB

// ------------------------------------------------------- core: 4 px per call
// Quad-task g: h = g/14, w0 = 4*(g%14); pixels (h, w0..w0+3).
// lora1 = Wh0@(h+1,w+1) + Wh1@(h, w-1|57) + Wh2@(h-1|57, w)
// lora2 = Wv0@(h+1,w+1) + Wv1@(h-1|57, w) + Wv2@(h, w-1|57)
// small = Wid@(h+1,w+1)
// Padded pos y,x -> tile rows y..y+2, tile cols x+2..x+4.
__device__ __forceinline__ void conv_quad(const float* __restrict__ tile,
        const float* __restrict__ wk, int g,
        float* __restrict__ l1, float* __restrict__ l2,
        float* __restrict__ sm, float* __restrict__ res)
{
    int h  = g / 14;
    int wq = g - h*14;
    int w0 = wq * 4;
    bool topwrap = (h == 0);
    #pragma unroll
    for (int p = 0; p < 4; ++p) { l1[p]=0.f; l2[p]=0.f; sm[p]=0.f; }

    {   // d = -1 row (posB wrow0)
        int row = topwrap ? 57 : (h-1);
        const float* rp = tile + row*TSTR + w0;
        float4 qa = *(const float4*)rp;
        float4 qb = *(const float4*)(rp+4);
        float X[8] = {qa.x,qa.y,qa.z,qa.w,qb.x,qb.y,qb.z,qb.w};
        #pragma unroll
        for (int p = 0; p < 4; ++p)
            #pragma unroll
            for (int j = 0; j < 3; ++j) {
                float v = X[2+p+j];
                l1[p] = fmaf(v, wk[18+j], l1[p]);
                l2[p] = fmaf(v, wk[36+j], l2[p]);
            }
    }
    #pragma unroll
    for (int d = 0; d < 4; ++d) {
        const float* rp = tile + (h+d)*TSTR + w0;
        float4 qa = *(const float4*)rp;
        float4 qb = *(const float4*)(rp+4);
        float X[9] = {qa.x,qa.y,qa.z,qa.w,qb.x,qb.y,qb.z,qb.w,0.f};
        if (d >= 1) X[8] = rp[8];
        if (d == 2) { res[0]=X[4]; res[1]=X[5]; res[2]=X[6]; res[3]=X[7]; }
        if (d <= 1) {   // posB wrow d+1 (masked when h==0)
            #pragma unroll
            for (int p = 0; p < 4; ++p)
                #pragma unroll
                for (int j = 0; j < 3; ++j) {
                    float v = topwrap ? 0.f : X[2+p+j];
                    l1[p] = fmaf(v, wk[21+3*d+j], l1[p]);
                    l2[p] = fmaf(v, wk[39+3*d+j], l2[p]);
                }
        }
        if (d <= 2) {   // posA wrow d
            #pragma unroll
            for (int p = 0; p < 4; ++p)
                #pragma unroll
                for (int j = 0; j < 3; ++j) {
                    float v = X[1+p+j];
                    l1[p] = fmaf(v, wk[9+3*d+j],  l1[p]);
                    l2[p] = fmaf(v, wk[45+3*d+j], l2[p]);
                }
        }
        if (d >= 1) {   // pos0 wrow d-1
            #pragma unroll
            for (int p = 0; p < 4; ++p)
                #pragma unroll
                for (int j = 0; j < 3; ++j) {
                    float v = X[3+p+j];
                    l1[p] = fmaf(v, wk[3*(d-1)+j],    l1[p]);
                    l2[p] = fmaf(v, wk[27+3*(d-1)+j], l2[p]);
                    sm[p] = fmaf(v, wk[54+3*(d-1)+j], sm[p]);
                }
        }
    }
    if (wq == 0) {  // w==0 wrap correction, pixel 0 only
        #pragma unroll
        for (int d = 0; d < 3; ++d) {
            float v = tile[(h+d)*TSTR + 59];
            l1[0] = fmaf(v, wk[9+3*d],  l1[0]);
            l2[0] = fmaf(v, wk[45+3*d], l2[0]);
        }
    }
}

// -------------------------------------------------- K1: conv ONCE + partials
__global__ void __launch_bounds__(256) k_conv(const float* __restrict__ in,
        const float* __restrict__ w0g, const float* __restrict__ w1g,
        const int* __restrict__ Mh, const int* __restrict__ Mv,
        const int* __restrict__ Mid, const int* __restrict__ rep_idx,
        float* __restrict__ ws)
{
    __shared__ __align__(16) float tile[TSZ];
    __shared__ float wkl[63];
    __shared__ float red[4][6];
    int bid = blockIdx.x;
    int r = bid % REPN;
    int b = bid / REPN;
    int tid = threadIdx.x;
    int cin = rep_idx[r];

    // effective weights for this r (folded k_weff), threads 0..62
    if (tid < 63) {
        int t  = tid / 9;
        int ij = tid % 9;
        const int* M = (t < 3) ? (Mh + (t*REPN + r)*NKn)
                     : (t < 6) ? (Mv + ((t-3)*REPN + r)*NKn)
                               : (Mid + r*NKn);
        float acc = 0.f;
        #pragma unroll
        for (int k = 0; k < NKn; ++k) {
            int m = M[k];
            acc += (float)m * (w0g[(r*NKn + k)*9 + ij] + w1g[(r*NKn + k)*9 + ij]);
        }
        wkl[tid] = acc;
    }
    // stage tile
    for (int i = tid; i < TSZ/4; i += 256) *(float4*)(tile + 4*i) = make_float4(0,0,0,0);
    __syncthreads();
    const float4* s4 = (const float4*)(in + ((size_t)(b*Cn + cin))*HWn);
    for (int i = tid; i < HWn/4; i += 256) {
        float4 v = s4[i];
        int e = i * 4;
        int row = e / Wn;
        int col = e % Wn;
        *(float4*)(tile + (2 + row)*TSTR + 4 + col) = v;
    }
    __syncthreads();

    float wk[63];
    #pragma unroll
    for (int i = 0; i < 63; ++i) wk[i] = wkl[i];

    size_t base = (size_t)(b*REPN + r)*HWn;
    float4* p1 = (float4*)(ws + L1_OFF + base);
    float4* p2 = (float4*)(ws + L2_OFF + base);
    float4* p3 = (float4*)(ws + SM_OFF + base);

    float s1=0.f,q1=0.f,s2=0.f,q2=0.f,s3=0.f,q3=0.f;
    for (int g = tid; g < NQ; g += 256) {
        float l1[4], l2[4], sm[4], res[4];
        conv_quad(tile, wk, g, l1, l2, sm, res);
        p1[g] = make_float4(l1[0],l1[1],l1[2],l1[3]);
        p2[g] = make_float4(l2[0],l2[1],l2[2],l2[3]);
        p3[g] = make_float4(sm[0],sm[1],sm[2],sm[3]);
        #pragma unroll
        for (int p = 0; p < 4; ++p) {
            s1 += l1[p]; q1 += l1[p]*l1[p];
            s2 += l2[p]; q2 += l2[p]*l2[p];
            s3 += sm[p]; q3 += sm[p]*sm[p];
        }
    }
    float vals[6] = {s1,q1,s2,q2,s3,q3};
    int lane = tid & 63, wave = tid >> 6;
    #pragma unroll
    for (int q = 0; q < 6; ++q) {
        float v = vals[q];
        for (int o = 32; o; o >>= 1) v += __shfl_down(v, o, 64);
        if (lane == 0) red[wave][q] = v;
    }
    __syncthreads();
    if (tid < 6)
        ws[PART_OFF + (tid*REPN + r)*Bn + b] =
            red[0][tid] + red[1][tid] + red[2][tid] + red[3][tid];
}

// ------------------------------------------------ K2: streaming normalize
__global__ void __launch_bounds__(256) k_final(const float* __restrict__ in,
        const int* __restrict__ rep_idx, const int* __restrict__ ghost_idx,
        const float* __restrict__ ws, float* __restrict__ out)
{
    int bid = blockIdx.x;
    int c = bid % Cn;
    int b = bid / Cn;
    int tid = threadIdx.x;

    if (c >= REPN) {                             // ghost channel copy
        int cin = ghost_idx[c - REPN];
        const float4* s4 = (const float4*)(in + ((size_t)(b*Cn + cin))*HWn);
        float4* d4 = (float4*)(out + ((size_t)(b*Cn + c))*HWn);
        for (int i = tid; i < HWn/4; i += 256) d4[i] = s4[i];
        return;
    }

    __shared__ float sred[6];
    int r = c;
    if (tid < 6) {
        const float* pp = ws + PART_OFF + (tid*REPN + r)*Bn;
        float s = 0.f;
        #pragma unroll
        for (int i = 0; i < Bn; ++i) s += pp[i];
        sred[tid] = s;
    }
    __syncthreads();
    const float inv = 1.0f / NSTATf;
    float m1 = sred[0]*inv, v1 = sred[1]*inv - m1*m1;
    float m2 = sred[2]*inv, v2 = sred[3]*inv - m2*m2;
    float m3 = sred[4]*inv, v3 = sred[5]*inv - m3*m3;
    float r1 = rsqrtf(v1 + EPSf), r2 = rsqrtf(v2 + EPSf), r3 = rsqrtf(v3 + EPSf);

    int cin = rep_idx[r];
    size_t base = (size_t)(b*REPN + r)*HWn;
    const float4* p1 = (const float4*)(ws + L1_OFF + base);
    const float4* p2 = (const float4*)(ws + L2_OFF + base);
    const float4* p3 = (const float4*)(ws + SM_OFF + base);
    const float4* rin = (const float4*)(in + ((size_t)(b*Cn + cin))*HWn);
    float4* d4 = (float4*)(out + ((size_t)(b*Cn + c))*HWn);

    for (int i = tid; i < HWn/4; i += 256) {
        float4 a = p1[i], d = p2[i], e = p3[i], x = rin[i];
        float4 o;
        o.x = (a.x-m1)*r1 + (d.x-m2)*r2 + (e.x-m3)*r3 + x.x;
        o.y = (a.y-m1)*r1 + (d.y-m2)*r2 + (e.y-m3)*r3 + x.y;
        o.z = (a.z-m1)*r1 + (d.z-m2)*r2 + (e.z-m3)*r3 + x.z;
        o.w = (a.w-m1)*r1 + (d.w-m2)*r2 + (e.w-m3)*r3 + x.w;
        d4[i] = o;
    }
}

extern "C" void kernel_launch(void* const* d_in, const int* in_sizes, int n_in,
                              void* d_out, int out_size, void* d_ws, size_t ws_size,
                              hipStream_t stream) {
    const float* in   = (const float*)d_in[0];
    const float* w0   = (const float*)d_in[1];
    const float* w1   = (const float*)d_in[2];
    const int*   Mh   = (const int*)d_in[3];
    const int*   Mv   = (const int*)d_in[4];
    const int*   Mid  = (const int*)d_in[5];
    const int*   ghost= (const int*)d_in[6];
    const int*   rep  = (const int*)d_in[7];
    float* out  = (float*)d_out;
    float* ws   = (float*)d_ws;

    k_conv<<<Bn*REPN, 256, 0, stream>>>(in, w0, w1, Mh, Mv, Mid, rep, ws);
    k_final<<<Bn*Cn, 256, 0, stream>>>(in, rep, ghost, ws, out);
}

// Round 4
// 124.986 us; speedup vs baseline: 1.1947x; 1.0884x over previous
//
#include <hip/hip_runtime.h>

#define Bn 32
#define Cn 64
#define Hn 56
#define Wn 56
#define REPN 50
#define NKn 17
#define HWn (Hn*Wn)           // 3136
#define NSTATf 100352.0f      // B*H*W
#define EPSf 1e-5f

// ws layout (floats)
#define PLANE (Bn*REPN*HWn)   // 5,017,600 floats
#define L1_OFF 0
#define L2_OFF PLANE
#define SM_OFF (2*PLANE)
#define PART_OFF (3*PLANE)            // [q(6)][r(50)][b(32)] = 9600 floats
#define WEFF_OFF (3*PLANE + 9600)     // 3150 floats [r][t(7)][9]

#define SEGH 7
#define SEGS 8                // 8*7 = 56 rows
#define NTASK (SEGS*14)       // 112 tasks per channel

// ---------------------------------------------------------------- K0: weights
__global__ void k_weff(const float* __restrict__ w0, const float* __restrict__ w1,
                       const int* __restrict__ Mh, const int* __restrict__ Mv,
                       const int* __restrict__ Mid, float* __restrict__ ws)
{
    int idx = blockIdx.x * blockDim.x + threadIdx.x;
    if (idx >= REPN*63) return;
    int r   = idx / 63;
    int rem = idx % 63;
    int t   = rem / 9;
    int ij  = rem % 9;
    const int* M = (t < 3) ? (Mh + (t*REPN + r)*NKn)
                 : (t < 6) ? (Mv + ((t-3)*REPN + r)*NKn)
                           : (Mid + r*NKn);
    float acc = 0.f;
    #pragma unroll
    for (int k = 0; k < NKn; ++k)
        acc += (float)M[k] * (w0[(r*NKn + k)*9 + ij] + w1[(r*NKn + k)*9 + ij]);
    ws[WEFF_OFF + idx] = acc;
}

// Load input row `row` of channel ch as window X[0..7] = cols 4q-3..4q+4
// (zeros outside [0,56)). Also c55 = input[row][55] for q==0 lanes.
__device__ __forceinline__ void load_row8c(const float* __restrict__ ch, int row, int q,
                                           float* __restrict__ X, float& c55)
{
    bool rv = (row >= 0) && (row < Hn);
    int rc = rv ? row : 0;
    const float* rp = ch + rc*Wn;
    float4 c0 = *(const float4*)(rp + (q ? 4*q - 4 : 0));   // cols 4q-4..4q-1
    float4 c1 = *(const float4*)(rp + 4*q);                 // cols 4q..4q+3
    int ox = (4*q + 4 <= 55) ? 4*q + 4 : 55;                // clamp in-row
    float cx = rp[ox];
    float mr = rv ? 1.f : 0.f;
    float m0 = (rv && q > 0)  ? 1.f : 0.f;
    float mx = (rv && q < 13) ? 1.f : 0.f;
    X[0]=c0.y*m0; X[1]=c0.z*m0; X[2]=c0.w*m0;
    X[3]=c1.x*mr; X[4]=c1.y*mr; X[5]=c1.z*mr; X[6]=c1.w*mr;
    X[7]=cx*mx;
    c55 = (q == 0) ? rp[55]*mr : 0.f;
}

// -------------------------------------------------- K1: conv once + partials
// Block = one (b,r) channel, 128 threads, 112 active tasks.
// Task: quad-column q (0..13), row segment seg (0..7), output rows h0..h0+6,
// pixels (h, 4q..4q+3). Rolling register window W[k] = input row h-3+k (k=0..4),
// 8 floats each = cols 4q-3..4q+4. C[k] = input[h-3+k][55] (q==0 lanes).
// Output pixel (h,w):
//  pos0 = conv(h+1,w+1): rows h-1..h+1 -> W[2+i], cols w-1+j -> X[p+2+j]
//  posA = conv(h, w-1|57): rows h-2..h -> W[1+i], cols w-3+j -> X[p+j]
//         w==0 wrap: + C[1+i]*wk[9+3i] (l1), *wk[45+3i] (l2)
//  posB = conv(h-1|57, w): rows h-3..h-1 -> W[i], cols w-2+j -> X[p+1+j]
//         h==0 wrap: + row55[w-2+j]*wk[18+j] (l1), *wk[36+j] (l2)
__global__ void __launch_bounds__(128) k_conv(const float* __restrict__ in,
        const int* __restrict__ rep_idx, float* __restrict__ ws)
{
    int bid = blockIdx.x;
    int r = bid % REPN;
    int b = bid / REPN;
    int tid = threadIdx.x;

    const float* wr = ws + WEFF_OFF + r*63;   // uniform -> s_load to SGPRs
    float wk[63];
    #pragma unroll
    for (int i = 0; i < 63; ++i) wk[i] = wr[i];

    int cin = rep_idx[r];
    const float* ch = in + ((size_t)(b*Cn + cin))*HWn;

    float s1=0.f,q1=0.f,s2=0.f,q2=0.f,s3=0.f,q3=0.f;

    if (tid < NTASK) {
        int seg = tid / 14;
        int q   = tid - seg*14;
        int h0  = seg * SEGH;
        bool top = (seg == 0);

        float W[5][8], C[5], T[8];
        {   // T = row 55 window (posB wrap for h==0); only seg 0 uses it
            float dummy;
            if (top) load_row8c(ch, 55, q, T, dummy);
        }
        #pragma unroll
        for (int k = 0; k < 5; ++k)
            load_row8c(ch, h0 - 3 + k, q, W[k], C[k]);

        size_t base = ((size_t)(b*REPN + r))*HWn;
        float* p1 = ws + L1_OFF + base;
        float* p2 = ws + L2_OFF + base;
        float* p3 = ws + SM_OFF + base;

        #pragma unroll
        for (int s = 0; s < SEGH; ++s) {
            int h = h0 + s;
            float Wn8[8], Cn1;
            load_row8c(ch, h + 2, q, Wn8, Cn1);   // prefetch next row

            float l1[4], l2[4], sm[4];
            #pragma unroll
            for (int p = 0; p < 4; ++p) { l1[p]=0.f; l2[p]=0.f; sm[p]=0.f; }
            #pragma unroll
            for (int i = 0; i < 3; ++i)
                #pragma unroll
                for (int j = 0; j < 3; ++j) {
                    float wh0 = wk[i*3+j],    wv0 = wk[27+i*3+j], wid = wk[54+i*3+j];
                    float wh1 = wk[9+i*3+j],  wv2 = wk[45+i*3+j];
                    float wh2 = wk[18+i*3+j], wv1 = wk[36+i*3+j];
                    #pragma unroll
                    for (int p = 0; p < 4; ++p) {
                        float a  = W[2+i][p+2+j];     // pos0
                        l1[p] = fmaf(a, wh0, l1[p]);
                        l2[p] = fmaf(a, wv0, l2[p]);
                        sm[p] = fmaf(a, wid, sm[p]);
                        float bA = W[1+i][p+j];       // posA
                        l1[p] = fmaf(bA, wh1, l1[p]);
                        l2[p] = fmaf(bA, wv2, l2[p]);
                        float bB = W[i][p+1+j];       // posB
                        l1[p] = fmaf(bB, wh2, l1[p]);
                        l2[p] = fmaf(bB, wv1, l2[p]);
                    }
                }
            if (q == 0) {   // col wrap, pixel 0 only
                #pragma unroll
                for (int i = 0; i < 3; ++i) {
                    l1[0] = fmaf(C[1+i], wk[9+3*i],  l1[0]);
                    l2[0] = fmaf(C[1+i], wk[45+3*i], l2[0]);
                }
            }
            if (s == 0 && top) {   // row wrap, h==0 only
                #pragma unroll
                for (int j = 0; j < 3; ++j)
                    #pragma unroll
                    for (int p = 0; p < 4; ++p) {
                        l1[p] = fmaf(T[p+1+j], wk[18+j], l1[p]);
                        l2[p] = fmaf(T[p+1+j], wk[36+j], l2[p]);
                    }
            }
            int o = h*Wn + 4*q;
            *(float4*)(p1 + o) = make_float4(l1[0],l1[1],l1[2],l1[3]);
            *(float4*)(p2 + o) = make_float4(l2[0],l2[1],l2[2],l2[3]);
            *(float4*)(p3 + o) = make_float4(sm[0],sm[1],sm[2],sm[3]);
            #pragma unroll
            for (int p = 0; p < 4; ++p) {
                s1 += l1[p]; q1 += l1[p]*l1[p];
                s2 += l2[p]; q2 += l2[p]*l2[p];
                s3 += sm[p]; q3 += sm[p]*sm[p];
            }
            #pragma unroll
            for (int k = 0; k < 4; ++k) {
                #pragma unroll
                for (int x = 0; x < 8; ++x) W[k][x] = W[k+1][x];
                C[k] = C[k+1];
            }
            #pragma unroll
            for (int x = 0; x < 8; ++x) W[4][x] = Wn8[x];
            C[4] = Cn1;
        }
    }

    __shared__ float red[2][6];
    float vals[6] = {s1,q1,s2,q2,s3,q3};
    int lane = tid & 63, wave = tid >> 6;
    #pragma unroll
    for (int v = 0; v < 6; ++v) {
        float x = vals[v];
        for (int o = 32; o; o >>= 1) x += __shfl_down(x, o, 64);
        if (lane == 0) red[wave][v] = x;
    }
    __syncthreads();
    if (tid < 6)
        ws[PART_OFF + (tid*REPN + r)*Bn + b] = red[0][tid] + red[1][tid];
}

// ------------------------------------------------ K2: streaming normalize
__global__ void __launch_bounds__(256) k_final(const float* __restrict__ in,
        const int* __restrict__ rep_idx, const int* __restrict__ ghost_idx,
        const float* __restrict__ ws, float* __restrict__ out)
{
    int bid = blockIdx.x;
    int c = bid % Cn;
    int b = bid / Cn;
    int tid = threadIdx.x;

    if (c >= REPN) {                             // ghost channel copy
        int cin = ghost_idx[c - REPN];
        const float4* s4 = (const float4*)(in + ((size_t)(b*Cn + cin))*HWn);
        float4* d4 = (float4*)(out + ((size_t)(b*Cn + c))*HWn);
        for (int i = tid; i < HWn/4; i += 256) d4[i] = s4[i];
        return;
    }

    __shared__ float sred[6];
    int r = c;
    if (tid < 6) {
        const float* pp = ws + PART_OFF + (tid*REPN + r)*Bn;
        float s = 0.f;
        #pragma unroll
        for (int i = 0; i < Bn; ++i) s += pp[i];
        sred[tid] = s;
    }
    __syncthreads();
    const float inv = 1.0f / NSTATf;
    float m1 = sred[0]*inv, v1 = sred[1]*inv - m1*m1;
    float m2 = sred[2]*inv, v2 = sred[3]*inv - m2*m2;
    float m3 = sred[4]*inv, v3 = sred[5]*inv - m3*m3;
    float r1 = rsqrtf(v1 + EPSf), r2 = rsqrtf(v2 + EPSf), r3 = rsqrtf(v3 + EPSf);

    int cin = rep_idx[r];
    size_t base = (size_t)(b*REPN + r)*HWn;
    const float4* p1 = (const float4*)(ws + L1_OFF + base);
    const float4* p2 = (const float4*)(ws + L2_OFF + base);
    const float4* p3 = (const float4*)(ws + SM_OFF + base);
    const float4* rin = (const float4*)(in + ((size_t)(b*Cn + cin))*HWn);
    float4* d4 = (float4*)(out + ((size_t)(b*Cn + c))*HWn);

    for (int i = tid; i < HWn/4; i += 256) {
        float4 a = p1[i], d = p2[i], e = p3[i], x = rin[i];
        float4 o;
        o.x = (a.x-m1)*r1 + (d.x-m2)*r2 + (e.x-m3)*r3 + x.x;
        o.y = (a.y-m1)*r1 + (d.y-m2)*r2 + (e.y-m3)*r3 + x.y;
        o.z = (a.z-m1)*r1 + (d.z-m2)*r2 + (e.z-m3)*r3 + x.z;
        o.w = (a.w-m1)*r1 + (d.w-m2)*r2 + (e.w-m3)*r3 + x.w;
        d4[i] = o;
    }
}

extern "C" void kernel_launch(void* const* d_in, const int* in_sizes, int n_in,
                              void* d_out, int out_size, void* d_ws, size_t ws_size,
                              hipStream_t stream) {
    const float* in   = (const float*)d_in[0];
    const float* w0   = (const float*)d_in[1];
    const float* w1   = (const float*)d_in[2];
    const int*   Mh   = (const int*)d_in[3];
    const int*   Mv   = (const int*)d_in[4];
    const int*   Mid  = (const int*)d_in[5];
    const int*   ghost= (const int*)d_in[6];
    const int*   rep  = (const int*)d_in[7];
    float* out  = (float*)d_out;
    float* ws   = (float*)d_ws;

    k_weff<<<(REPN*63 + 255)/256, 256, 0, stream>>>(w0, w1, Mh, Mv, Mid, ws);
    k_conv<<<Bn*REPN, 128, 0, stream>>>(in, rep, ws);
    k_final<<<Bn*Cn, 256, 0, stream>>>(in, rep, ghost, ws, out);
}

// Round 5
// 124.722 us; speedup vs baseline: 1.1972x; 1.0021x over previous
//
#include <hip/hip_runtime.h>

#define Bn 32
#define Cn 64
#define Hn 56
#define Wn 56
#define REPN 50
#define NKn 17
#define HWn (Hn*Wn)           // 3136
#define NSTATf 100352.0f      // B*H*W
#define EPSf 1e-5f

// ws layout (floats) — tiny now; every slot written unconditionally
#define PART_OFF 0            // [q(6)][r(50)][b(32)] = 9600
#define WEFF_OFF 9600         // [r(50)][t(7)][9] = 3150

#define SEGH 7
#define NTASK 112             // 8 row-segments * 14 quad-cols

// ---------------------------------------------------------------- K0: weights
__global__ void k_weff(const float* __restrict__ w0, const float* __restrict__ w1,
                       const int* __restrict__ Mh, const int* __restrict__ Mv,
                       const int* __restrict__ Mid, float* __restrict__ ws)
{
    int idx = blockIdx.x * blockDim.x + threadIdx.x;
    if (idx >= REPN*63) return;
    int r   = idx / 63;
    int rem = idx % 63;
    int t   = rem / 9;
    int ij  = rem % 9;
    const int* M = (t < 3) ? (Mh + (t*REPN + r)*NKn)
                 : (t < 6) ? (Mv + ((t-3)*REPN + r)*NKn)
                           : (Mid + r*NKn);
    float acc = 0.f;
    #pragma unroll
    for (int k = 0; k < NKn; ++k)
        acc += (float)M[k] * (w0[(r*NKn + k)*9 + ij] + w1[(r*NKn + k)*9 + ij]);
    ws[WEFF_OFF + idx] = acc;
}

// Load input row `row` of channel ch as window X[0..7] = cols 4q-3..4q+4
// (zeros outside [0,56)). Also c55 = input[row][55] for q==0 lanes.
__device__ __forceinline__ void load_row8c(const float* __restrict__ ch, int row, int q,
                                           float* __restrict__ X, float& c55)
{
    bool rv = (row >= 0) && (row < Hn);
    int rc = rv ? row : 0;
    const float* rp = ch + rc*Wn;
    float4 c0 = *(const float4*)(rp + (q ? 4*q - 4 : 0));   // cols 4q-4..4q-1
    float4 c1 = *(const float4*)(rp + 4*q);                 // cols 4q..4q+3
    int ox = (4*q + 4 <= 55) ? 4*q + 4 : 55;                // clamp in-row
    float cx = rp[ox];
    float mr = rv ? 1.f : 0.f;
    float m0 = (rv && q > 0)  ? 1.f : 0.f;
    float mx = (rv && q < 13) ? 1.f : 0.f;
    X[0]=c0.y*m0; X[1]=c0.z*m0; X[2]=c0.w*m0;
    X[3]=c1.x*mr; X[4]=c1.y*mr; X[5]=c1.z*mr; X[6]=c1.w*mr;
    X[7]=cx*mx;
    c55 = (q == 0) ? rp[55]*mr : 0.f;
}

// ---------------------------------------------------- register-walk conv core
// Task tid (<112): quad-col q (0..13), row segment seg (0..7), output rows
// h0..h0+6, pixels (h, 4q..4q+3). Rolling window W[k] = input row h-3+k,
// 8 floats = cols 4q-3..4q+4. C[k] = input[h-3+k][55] (q==0 lanes only).
//  pos0 = conv(h+1,w+1): rows W[2+i], cols X[p+2+j]   (l1,l2,sm)
//  posA = conv(h, w-1|57): rows W[1+i], cols X[p+j]   (l1,l2); w==0 wrap +C
//  posB = conv(h-1|57, w): rows W[i], cols X[p+1+j]   (l1,l2); h==0 wrap +T
// res[p] = input[h][4q+p] = W[3][3+p] — the residual, free.
template <typename F>
__device__ __forceinline__ void conv_walk(const float* __restrict__ ch,
        const float (&wk)[63], int tid, F emit)
{
    if (tid >= NTASK) return;
    int seg = tid / 14;
    int q   = tid - seg*14;
    int h0  = seg * SEGH;
    bool top = (seg == 0);

    float W[5][8], C[5], T[8];
    {
        float dummy;
        if (top) load_row8c(ch, 55, q, T, dummy);
    }
    #pragma unroll
    for (int k = 0; k < 5; ++k)
        load_row8c(ch, h0 - 3 + k, q, W[k], C[k]);

    #pragma unroll
    for (int s = 0; s < SEGH; ++s) {
        int h = h0 + s;
        float Wn8[8], Cn1;
        load_row8c(ch, h + 2, q, Wn8, Cn1);   // prefetch next row

        float l1[4], l2[4], sm[4];
        #pragma unroll
        for (int p = 0; p < 4; ++p) { l1[p]=0.f; l2[p]=0.f; sm[p]=0.f; }
        #pragma unroll
        for (int i = 0; i < 3; ++i)
            #pragma unroll
            for (int j = 0; j < 3; ++j) {
                float wh0 = wk[i*3+j],    wv0 = wk[27+i*3+j], wid = wk[54+i*3+j];
                float wh1 = wk[9+i*3+j],  wv2 = wk[45+i*3+j];
                float wh2 = wk[18+i*3+j], wv1 = wk[36+i*3+j];
                #pragma unroll
                for (int p = 0; p < 4; ++p) {
                    float a  = W[2+i][p+2+j];     // pos0
                    l1[p] = fmaf(a, wh0, l1[p]);
                    l2[p] = fmaf(a, wv0, l2[p]);
                    sm[p] = fmaf(a, wid, sm[p]);
                    float bA = W[1+i][p+j];       // posA
                    l1[p] = fmaf(bA, wh1, l1[p]);
                    l2[p] = fmaf(bA, wv2, l2[p]);
                    float bB = W[i][p+1+j];       // posB
                    l1[p] = fmaf(bB, wh2, l1[p]);
                    l2[p] = fmaf(bB, wv1, l2[p]);
                }
            }
        if (q == 0) {   // col wrap, pixel 0 only
            #pragma unroll
            for (int i = 0; i < 3; ++i) {
                l1[0] = fmaf(C[1+i], wk[9+3*i],  l1[0]);
                l2[0] = fmaf(C[1+i], wk[45+3*i], l2[0]);
            }
        }
        if (s == 0 && top) {   // row wrap, h==0 only
            #pragma unroll
            for (int j = 0; j < 3; ++j)
                #pragma unroll
                for (int p = 0; p < 4; ++p) {
                    l1[p] = fmaf(T[p+1+j], wk[18+j], l1[p]);
                    l2[p] = fmaf(T[p+1+j], wk[36+j], l2[p]);
                }
        }
        float res[4] = {W[3][3], W[3][4], W[3][5], W[3][6]};
        emit(h, q, l1, l2, sm, res);

        #pragma unroll
        for (int k = 0; k < 4; ++k) {
            #pragma unroll
            for (int x = 0; x < 8; ++x) W[k][x] = W[k+1][x];
            C[k] = C[k+1];
        }
        #pragma unroll
        for (int x = 0; x < 8; ++x) W[4][x] = Wn8[x];
        C[4] = Cn1;
    }
}

// -------------------------------------------- K1: stats only (no plane store)
__global__ void __launch_bounds__(128) k_stats(const float* __restrict__ in,
        const int* __restrict__ rep_idx, float* __restrict__ ws)
{
    int bid = blockIdx.x;
    int r = bid % REPN;
    int b = bid / REPN;
    int tid = threadIdx.x;

    const float* wr = ws + WEFF_OFF + r*63;   // block-uniform
    float wk[63];
    #pragma unroll
    for (int i = 0; i < 63; ++i) wk[i] = wr[i];

    int cin = rep_idx[r];
    const float* ch = in + ((size_t)(b*Cn + cin))*HWn;

    float s1=0.f,q1=0.f,s2=0.f,q2=0.f,s3=0.f,q3=0.f;
    conv_walk(ch, wk, tid,
        [&](int h, int q, float* l1, float* l2, float* sm, float* res) {
            (void)h; (void)q; (void)res;
            #pragma unroll
            for (int p = 0; p < 4; ++p) {
                s1 += l1[p]; q1 += l1[p]*l1[p];
                s2 += l2[p]; q2 += l2[p]*l2[p];
                s3 += sm[p]; q3 += sm[p]*sm[p];
            }
        });

    __shared__ float red[2][6];
    float vals[6] = {s1,q1,s2,q2,s3,q3};
    int lane = tid & 63, wave = tid >> 6;
    #pragma unroll
    for (int v = 0; v < 6; ++v) {
        float x = vals[v];
        for (int o = 32; o; o >>= 1) x += __shfl_down(x, o, 64);
        if (lane == 0) red[wave][v] = x;
    }
    __syncthreads();
    if (tid < 6)
        ws[PART_OFF + (tid*REPN + r)*Bn + b] = red[0][tid] + red[1][tid];
}

// ----------------------------------- K2: recompute conv + normalize + output
__global__ void __launch_bounds__(128) k_out(const float* __restrict__ in,
        const int* __restrict__ rep_idx, const int* __restrict__ ghost_idx,
        const float* __restrict__ ws, float* __restrict__ out)
{
    int bid = blockIdx.x;
    int c = bid % Cn;
    int b = bid / Cn;
    int tid = threadIdx.x;

    if (c >= REPN) {                             // ghost channel copy
        int cin = ghost_idx[c - REPN];
        const float4* s4 = (const float4*)(in + ((size_t)(b*Cn + cin))*HWn);
        float4* d4 = (float4*)(out + ((size_t)(b*Cn + c))*HWn);
        for (int i = tid; i < HWn/4; i += 128) d4[i] = s4[i];
        return;
    }

    int r = c;
    __shared__ float sred[6];
    if (tid < 6) {
        const float* pp = ws + PART_OFF + (tid*REPN + r)*Bn;
        float s = 0.f;
        #pragma unroll
        for (int i = 0; i < Bn; ++i) s += pp[i];
        sred[tid] = s;
    }
    __syncthreads();
    const float inv = 1.0f / NSTATf;
    float m1 = sred[0]*inv, v1 = sred[1]*inv - m1*m1;
    float m2 = sred[2]*inv, v2 = sred[3]*inv - m2*m2;
    float m3 = sred[4]*inv, v3 = sred[5]*inv - m3*m3;
    float r1 = rsqrtf(v1 + EPSf), r2 = rsqrtf(v2 + EPSf), r3 = rsqrtf(v3 + EPSf);

    const float* wr = ws + WEFF_OFF + r*63;
    float wk[63];
    #pragma unroll
    for (int i = 0; i < 63; ++i) wk[i] = wr[i];

    int cin = rep_idx[r];
    const float* ch = in + ((size_t)(b*Cn + cin))*HWn;
    float* dst = out + ((size_t)(b*Cn + c))*HWn;

    conv_walk(ch, wk, tid,
        [&](int h, int q, float* l1, float* l2, float* sm, float* res) {
            float4 o;
            o.x = (l1[0]-m1)*r1 + (l2[0]-m2)*r2 + (sm[0]-m3)*r3 + res[0];
            o.y = (l1[1]-m1)*r1 + (l2[1]-m2)*r2 + (sm[1]-m3)*r3 + res[1];
            o.z = (l1[2]-m1)*r1 + (l2[2]-m2)*r2 + (sm[2]-m3)*r3 + res[2];
            o.w = (l1[3]-m1)*r1 + (l2[3]-m2)*r2 + (sm[3]-m3)*r3 + res[3];
            *(float4*)(dst + h*Wn + 4*q) = o;
        });
}

extern "C" void kernel_launch(void* const* d_in, const int* in_sizes, int n_in,
                              void* d_out, int out_size, void* d_ws, size_t ws_size,
                              hipStream_t stream) {
    const float* in   = (const float*)d_in[0];
    const float* w0   = (const float*)d_in[1];
    const float* w1   = (const float*)d_in[2];
    const int*   Mh   = (const int*)d_in[3];
    const int*   Mv   = (const int*)d_in[4];
    const int*   Mid  = (const int*)d_in[5];
    const int*   ghost= (const int*)d_in[6];
    const int*   rep  = (const int*)d_in[7];
    float* out  = (float*)d_out;
    float* ws   = (float*)d_ws;

    k_weff<<<(REPN*63 + 127)/128, 128, 0, stream>>>(w0, w1, Mh, Mv, Mid, ws);
    k_stats<<<Bn*REPN, 128, 0, stream>>>(in, rep, ws);
    k_out<<<Bn*Cn, 128, 0, stream>>>(in, rep, ghost, ws, out);
}

// Round 7
// 124.320 us; speedup vs baseline: 1.2011x; 1.0032x over previous
//
#include <hip/hip_runtime.h>
#include <hip/hip_cooperative_groups.h>

namespace cg = cooperative_groups;

#define Bn 32
#define Cn 64
#define Hn 56
#define Wn 56
#define REPN 50
#define NKn 17
#define HWn (Hn*Wn)           // 3136
#define NSTATf 100352.0f      // B*H*W
#define EPSf 1e-5f

// ws layout (floats) — every slot written unconditionally before any read
#define PART_OFF 0            // [q(6)][r(50)][b(32)] = 9600
#define WEFF_OFF 9600         // [r(50)][t(7)][9] = 3150

#define SEGH 7
#define NTASK 112             // 8 row-segments * 14 quad-cols

// ------------------------------------------------------------ weff compute
__device__ __forceinline__ void weff_one(int idx,
        const float* __restrict__ w0, const float* __restrict__ w1,
        const int* __restrict__ Mh, const int* __restrict__ Mv,
        const int* __restrict__ Mid, float* __restrict__ ws)
{
    int r   = idx / 63;
    int rem = idx % 63;
    int t   = rem / 9;
    int ij  = rem % 9;
    const int* M = (t < 3) ? (Mh + (t*REPN + r)*NKn)
                 : (t < 6) ? (Mv + ((t-3)*REPN + r)*NKn)
                           : (Mid + r*NKn);
    float acc = 0.f;
    #pragma unroll
    for (int k = 0; k < NKn; ++k)
        acc += (float)M[k] * (w0[(r*NKn + k)*9 + ij] + w1[(r*NKn + k)*9 + ij]);
    ws[WEFF_OFF + idx] = acc;
}

__global__ void k_weff(const float* __restrict__ w0, const float* __restrict__ w1,
                       const int* __restrict__ Mh, const int* __restrict__ Mv,
                       const int* __restrict__ Mid, float* __restrict__ ws)
{
    int idx = blockIdx.x * blockDim.x + threadIdx.x;
    if (idx < REPN*63) weff_one(idx, w0, w1, Mh, Mv, Mid, ws);
}

// Load input row `row` of channel ch as window X[0..7] = cols 4q-3..4q+4
// (zeros outside [0,56)). Also c55 = input[row][55] for q==0 lanes.
__device__ __forceinline__ void load_row8c(const float* __restrict__ ch, int row, int q,
                                           float* __restrict__ X, float& c55)
{
    bool rv = (row >= 0) && (row < Hn);
    int rc = rv ? row : 0;
    const float* rp = ch + rc*Wn;
    float4 c0 = *(const float4*)(rp + (q ? 4*q - 4 : 0));   // cols 4q-4..4q-1
    float4 c1 = *(const float4*)(rp + 4*q);                 // cols 4q..4q+3
    int ox = (4*q + 4 <= 55) ? 4*q + 4 : 55;                // clamp in-row
    float cx = rp[ox];
    float mr = rv ? 1.f : 0.f;
    float m0 = (rv && q > 0)  ? 1.f : 0.f;
    float mx = (rv && q < 13) ? 1.f : 0.f;
    X[0]=c0.y*m0; X[1]=c0.z*m0; X[2]=c0.w*m0;
    X[3]=c1.x*mr; X[4]=c1.y*mr; X[5]=c1.z*mr; X[6]=c1.w*mr;
    X[7]=cx*mx;
    c55 = (q == 0) ? rp[55]*mr : 0.f;
}

// ---------------------------------------------------- register-walk conv core
// Task tid (<112): quad-col q (0..13), row segment seg (0..7), output rows
// h0..h0+6, pixels (h, 4q..4q+3). Rolling window W[k] = input row h-3+k,
// 8 floats = cols 4q-3..4q+4. C[k] = input[h-3+k][55] (q==0 lanes only).
//  pos0 = conv(h+1,w+1): rows W[2+i], cols X[p+2+j]   (l1,l2,sm)
//  posA = conv(h, w-1|57): rows W[1+i], cols X[p+j]   (l1,l2); w==0 wrap +C
//  posB = conv(h-1|57, w): rows W[i], cols X[p+1+j]   (l1,l2); h==0 wrap +T
// res[p] = input[h][4q+p] = W[3][3+p] — the residual, free.
template <typename F>
__device__ __forceinline__ void conv_walk(const float* __restrict__ ch,
        const float (&wk)[63], int tid, F emit)
{
    if (tid >= NTASK) return;
    int seg = tid / 14;
    int q   = tid - seg*14;
    int h0  = seg * SEGH;
    bool top = (seg == 0);

    float W[5][8], C[5], T[8];
    {
        float dummy;
        if (top) load_row8c(ch, 55, q, T, dummy);
    }
    #pragma unroll
    for (int k = 0; k < 5; ++k)
        load_row8c(ch, h0 - 3 + k, q, W[k], C[k]);

    #pragma unroll
    for (int s = 0; s < SEGH; ++s) {
        int h = h0 + s;
        float Wn8[8], Cn1;
        load_row8c(ch, h + 2, q, Wn8, Cn1);   // prefetch next row

        float l1[4], l2[4], sm[4];
        #pragma unroll
        for (int p = 0; p < 4; ++p) { l1[p]=0.f; l2[p]=0.f; sm[p]=0.f; }
        #pragma unroll
        for (int i = 0; i < 3; ++i)
            #pragma unroll
            for (int j = 0; j < 3; ++j) {
                float wh0 = wk[i*3+j],    wv0 = wk[27+i*3+j], wid = wk[54+i*3+j];
                float wh1 = wk[9+i*3+j],  wv2 = wk[45+i*3+j];
                float wh2 = wk[18+i*3+j], wv1 = wk[36+i*3+j];
                #pragma unroll
                for (int p = 0; p < 4; ++p) {
                    float a  = W[2+i][p+2+j];     // pos0
                    l1[p] = fmaf(a, wh0, l1[p]);
                    l2[p] = fmaf(a, wv0, l2[p]);
                    sm[p] = fmaf(a, wid, sm[p]);
                    float bA = W[1+i][p+j];       // posA
                    l1[p] = fmaf(bA, wh1, l1[p]);
                    l2[p] = fmaf(bA, wv2, l2[p]);
                    float bB = W[i][p+1+j];       // posB
                    l1[p] = fmaf(bB, wh2, l1[p]);
                    l2[p] = fmaf(bB, wv1, l2[p]);
                }
            }
        if (q == 0) {   // col wrap, pixel 0 only
            #pragma unroll
            for (int i = 0; i < 3; ++i) {
                l1[0] = fmaf(C[1+i], wk[9+3*i],  l1[0]);
                l2[0] = fmaf(C[1+i], wk[45+3*i], l2[0]);
            }
        }
        if (s == 0 && top) {   // row wrap, h==0 only
            #pragma unroll
            for (int j = 0; j < 3; ++j)
                #pragma unroll
                for (int p = 0; p < 4; ++p) {
                    l1[p] = fmaf(T[p+1+j], wk[18+j], l1[p]);
                    l2[p] = fmaf(T[p+1+j], wk[36+j], l2[p]);
                }
        }
        float res[4] = {W[3][3], W[3][4], W[3][5], W[3][6]};
        emit(h, q, l1, l2, sm, res);

        #pragma unroll
        for (int k = 0; k < 4; ++k) {
            #pragma unroll
            for (int x = 0; x < 8; ++x) W[k][x] = W[k+1][x];
            C[k] = C[k+1];
        }
        #pragma unroll
        for (int x = 0; x < 8; ++x) W[4][x] = Wn8[x];
        C[4] = Cn1;
    }
}

// ------------------------------------------- fused cooperative single kernel
// Grid 1024 x 128 (2 waves/block). __launch_bounds__(128,2) -> 4 blocks/CU
// co-residency needed; VGPR cap 256 (no spill pressure) -> large occupancy
// margin so the cooperative-launch validation accepts.
// Phase 0: weff. sync. Phase 1: stats partials (+ghost copies). sync.
// Phase 2: finalize BN, recompute conv, write output.
__global__ void __launch_bounds__(128, 2) k_fused(const float* __restrict__ in,
        const float* __restrict__ w0, const float* __restrict__ w1,
        const int* __restrict__ Mh, const int* __restrict__ Mv,
        const int* __restrict__ Mid,
        const int* __restrict__ rep_idx, const int* __restrict__ ghost_idx,
        float* __restrict__ ws, float* __restrict__ out)
{
    cg::grid_group grid = cg::this_grid();
    int tid = threadIdx.x;

    // ---- phase 0: effective weights
    {
        int gidx = blockIdx.x * 128 + tid;
        if (gidx < REPN*63) weff_one(gidx, w0, w1, Mh, Mv, Mid, ws);
    }
    grid.sync();

    __shared__ float red[2][6];
    // ---- phase 1: partial stats (rep) / copy (ghost), 2 tasks per block
    #pragma unroll
    for (int it = 0; it < 2; ++it) {
        int v = blockIdx.x*2 + it;
        int c = v & 63;
        int b = v >> 6;
        if (c >= REPN) {
            int cin = ghost_idx[c - REPN];
            const float4* s4 = (const float4*)(in + ((size_t)(b*Cn + cin))*HWn);
            float4* d4 = (float4*)(out + ((size_t)(b*Cn + c))*HWn);
            for (int i = tid; i < HWn/4; i += 128) d4[i] = s4[i];
            continue;
        }
        int r = c;
        const float* wr = ws + WEFF_OFF + r*63;
        float wk[63];
        #pragma unroll
        for (int i = 0; i < 63; ++i) wk[i] = wr[i];
        const float* ch = in + ((size_t)(b*Cn + rep_idx[r]))*HWn;

        float s1=0.f,q1=0.f,s2=0.f,q2=0.f,s3=0.f,q3=0.f;
        conv_walk(ch, wk, tid,
            [&](int h, int q, float* l1, float* l2, float* sm, float* res) {
                (void)h; (void)q; (void)res;
                #pragma unroll
                for (int p = 0; p < 4; ++p) {
                    s1 += l1[p]; q1 += l1[p]*l1[p];
                    s2 += l2[p]; q2 += l2[p]*l2[p];
                    s3 += sm[p]; q3 += sm[p]*sm[p];
                }
            });
        __syncthreads();   // red[] safe to overwrite
        {
            float vals[6] = {s1,q1,s2,q2,s3,q3};
            int lane = tid & 63, wave = tid >> 6;
            #pragma unroll
            for (int x = 0; x < 6; ++x) {
                float y = vals[x];
                for (int o = 32; o; o >>= 1) y += __shfl_down(y, o, 64);
                if (lane == 0) red[wave][x] = y;
            }
        }
        __syncthreads();
        if (tid < 6)
            ws[PART_OFF + (tid*REPN + r)*Bn + b] = red[0][tid] + red[1][tid];
    }
    grid.sync();

    // ---- phase 2: finalize BN + recompute conv + write
    __shared__ float sred[6];
    #pragma unroll
    for (int it = 0; it < 2; ++it) {
        int v = blockIdx.x*2 + it;
        int c = v & 63;
        int b = v >> 6;
        if (c >= REPN) continue;
        int r = c;
        __syncthreads();   // sred[] safe to overwrite
        if (tid < 6) {
            const float* pp = ws + PART_OFF + (tid*REPN + r)*Bn;
            float s = 0.f;
            #pragma unroll
            for (int i = 0; i < Bn; ++i) s += pp[i];
            sred[tid] = s;
        }
        __syncthreads();
        const float inv = 1.0f / NSTATf;
        float m1 = sred[0]*inv, v1 = sred[1]*inv - m1*m1;
        float m2 = sred[2]*inv, v2 = sred[3]*inv - m2*m2;
        float m3 = sred[4]*inv, v3 = sred[5]*inv - m3*m3;
        float r1 = rsqrtf(v1 + EPSf), r2 = rsqrtf(v2 + EPSf), r3 = rsqrtf(v3 + EPSf);

        const float* wr = ws + WEFF_OFF + r*63;
        float wk[63];
        #pragma unroll
        for (int i = 0; i < 63; ++i) wk[i] = wr[i];
        const float* ch = in + ((size_t)(b*Cn + rep_idx[r]))*HWn;
        float* dst = out + ((size_t)(b*Cn + c))*HWn;

        conv_walk(ch, wk, tid,
            [&](int h, int q, float* l1, float* l2, float* sm, float* res) {
                float4 o;
                o.x = (l1[0]-m1)*r1 + (l2[0]-m2)*r2 + (sm[0]-m3)*r3 + res[0];
                o.y = (l1[1]-m1)*r1 + (l2[1]-m2)*r2 + (sm[1]-m3)*r3 + res[1];
                o.z = (l1[2]-m1)*r1 + (l2[2]-m2)*r2 + (sm[2]-m3)*r3 + res[2];
                o.w = (l1[3]-m1)*r1 + (l2[3]-m2)*r2 + (sm[3]-m3)*r3 + res[3];
                *(float4*)(dst + h*Wn + 4*q) = o;
            });
    }
}

// ------------------------------------- fallback kernels (proven R5 structure)
__global__ void __launch_bounds__(128) k_stats(const float* __restrict__ in,
        const int* __restrict__ rep_idx, float* __restrict__ ws)
{
    int bid = blockIdx.x;
    int r = bid % REPN;
    int b = bid / REPN;
    int tid = threadIdx.x;

    const float* wr = ws + WEFF_OFF + r*63;
    float wk[63];
    #pragma unroll
    for (int i = 0; i < 63; ++i) wk[i] = wr[i];
    const float* ch = in + ((size_t)(b*Cn + rep_idx[r]))*HWn;

    float s1=0.f,q1=0.f,s2=0.f,q2=0.f,s3=0.f,q3=0.f;
    conv_walk(ch, wk, tid,
        [&](int h, int q, float* l1, float* l2, float* sm, float* res) {
            (void)h; (void)q; (void)res;
            #pragma unroll
            for (int p = 0; p < 4; ++p) {
                s1 += l1[p]; q1 += l1[p]*l1[p];
                s2 += l2[p]; q2 += l2[p]*l2[p];
                s3 += sm[p]; q3 += sm[p]*sm[p];
            }
        });

    __shared__ float red[2][6];
    float vals[6] = {s1,q1,s2,q2,s3,q3};
    int lane = tid & 63, wave = tid >> 6;
    #pragma unroll
    for (int v = 0; v < 6; ++v) {
        float x = vals[v];
        for (int o = 32; o; o >>= 1) x += __shfl_down(x, o, 64);
        if (lane == 0) red[wave][v] = x;
    }
    __syncthreads();
    if (tid < 6)
        ws[PART_OFF + (tid*REPN + r)*Bn + b] = red[0][tid] + red[1][tid];
}

__global__ void __launch_bounds__(128) k_out(const float* __restrict__ in,
        const int* __restrict__ rep_idx, const int* __restrict__ ghost_idx,
        const float* __restrict__ ws, float* __restrict__ out)
{
    int bid = blockIdx.x;
    int c = bid % Cn;
    int b = bid / Cn;
    int tid = threadIdx.x;

    if (c >= REPN) {
        int cin = ghost_idx[c - REPN];
        const float4* s4 = (const float4*)(in + ((size_t)(b*Cn + cin))*HWn);
        float4* d4 = (float4*)(out + ((size_t)(b*Cn + c))*HWn);
        for (int i = tid; i < HWn/4; i += 128) d4[i] = s4[i];
        return;
    }

    int r = c;
    __shared__ float sred[6];
    if (tid < 6) {
        const float* pp = ws + PART_OFF + (tid*REPN + r)*Bn;
        float s = 0.f;
        #pragma unroll
        for (int i = 0; i < Bn; ++i) s += pp[i];
        sred[tid] = s;
    }
    __syncthreads();
    const float inv = 1.0f / NSTATf;
    float m1 = sred[0]*inv, v1 = sred[1]*inv - m1*m1;
    float m2 = sred[2]*inv, v2 = sred[3]*inv - m2*m2;
    float m3 = sred[4]*inv, v3 = sred[5]*inv - m3*m3;
    float r1 = rsqrtf(v1 + EPSf), r2 = rsqrtf(v2 + EPSf), r3 = rsqrtf(v3 + EPSf);

    const float* wr = ws + WEFF_OFF + r*63;
    float wk[63];
    #pragma unroll
    for (int i = 0; i < 63; ++i) wk[i] = wr[i];
    const float* ch = in + ((size_t)(b*Cn + rep_idx[r]))*HWn;
    float* dst = out + ((size_t)(b*Cn + c))*HWn;

    conv_walk(ch, wk, tid,
        [&](int h, int q, float* l1, float* l2, float* sm, float* res) {
            float4 o;
            o.x = (l1[0]-m1)*r1 + (l2[0]-m2)*r2 + (sm[0]-m3)*r3 + res[0];
            o.y = (l1[1]-m1)*r1 + (l2[1]-m2)*r2 + (sm[1]-m3)*r3 + res[1];
            o.z = (l1[2]-m1)*r1 + (l2[2]-m2)*r2 + (sm[2]-m3)*r3 + res[2];
            o.w = (l1[3]-m1)*r1 + (l2[3]-m2)*r2 + (sm[3]-m3)*r3 + res[3];
            *(float4*)(dst + h*Wn + 4*q) = o;
        });
}

extern "C" void kernel_launch(void* const* d_in, const int* in_sizes, int n_in,
                              void* d_out, int out_size, void* d_ws, size_t ws_size,
                              hipStream_t stream) {
    const float* in   = (const float*)d_in[0];
    const float* w0   = (const float*)d_in[1];
    const float* w1   = (const float*)d_in[2];
    const int*   Mh   = (const int*)d_in[3];
    const int*   Mv   = (const int*)d_in[4];
    const int*   Mid  = (const int*)d_in[5];
    const int*   ghost= (const int*)d_in[6];
    const int*   rep  = (const int*)d_in[7];
    float* out  = (float*)d_out;
    float* ws   = (float*)d_ws;

    // Capture-safe occupancy gate: cooperative path needs 4 blocks/CU.
    int maxBlk = 0;
    hipError_t qerr = hipOccupancyMaxActiveBlocksPerMultiprocessor(
        &maxBlk, (const void*)k_fused, 128, 0);
    bool coop_ok = (qerr == hipSuccess) && (maxBlk >= 4);

    if (coop_ok) {
        void* args[] = { (void*)&in, (void*)&w0, (void*)&w1, (void*)&Mh,
                         (void*)&Mv, (void*)&Mid, (void*)&rep, (void*)&ghost,
                         (void*)&ws, (void*)&out };
        hipError_t lerr = hipLaunchCooperativeKernel((const void*)k_fused,
                              dim3(1024), dim3(128), args, 0, stream);
        if (lerr == hipSuccess) return;
    }
    // Fallback: proven 3-kernel chain
    k_weff<<<(REPN*63 + 127)/128, 128, 0, stream>>>(w0, w1, Mh, Mv, Mid, ws);
    k_stats<<<Bn*REPN, 128, 0, stream>>>(in, rep, ws);
    k_out<<<Bn*Cn, 128, 0, stream>>>(in, rep, ghost, ws, out);
}